// Round 5
// baseline (694.204 us; speedup 1.0000x reference)
//
#include <hip/hip_runtime.h>

typedef __bf16 bf16;
typedef __attribute__((ext_vector_type(8))) __bf16 bf16x8;
typedef __attribute__((ext_vector_type(4))) __bf16 bf16x4;
typedef __attribute__((ext_vector_type(4))) float fvec4;

#define MFMA16(a, b, c) __builtin_amdgcn_mfma_f32_16x16x32_bf16(a, b, c, 0, 0, 0)

__device__ __forceinline__ void glds16(const bf16* g, bf16* l) {
  __builtin_amdgcn_global_load_lds(
      (const __attribute__((address_space(1))) void*)g,
      (__attribute__((address_space(3))) void*)l, 16, 0, 0);
}

__device__ inline fvec4 zero4() { fvec4 z = {0.f, 0.f, 0.f, 0.f}; return z; }

// Workspace bf16 layout (elements):
//   wqkv : [1536][512] q/k/v rows contiguous @ 0        (786432)
//   wo   : [512][512]                        @ 786432   (262144)
//   posb : pq*gq / pk*gk / pv*gv2 [8][128][64] @ 1048576 (196608)
#define PREP_ELEMS 1245184

// R5: gates folded here (pq *= g_q, pk *= g_k, pv *= g_v2) so the hot
// kernel does straight loads/adds. Gates are broadcast scalar loads.
__global__ __launch_bounds__(512) void prep_kernel(
    const float* __restrict__ qw, const float* __restrict__ kw,
    const float* __restrict__ vw, const float* __restrict__ ow,
    const float* __restrict__ pq, const float* __restrict__ pk,
    const float* __restrict__ pv,
    const float* __restrict__ g_q, const float* __restrict__ g_k,
    const float* __restrict__ g_v2, bf16* __restrict__ dst)
{
  int i = (blockIdx.x * 512 + threadIdx.x) * 4;
  const float* s;
  float sc = 1.f;
  if      (i < 262144)  s = qw + i;
  else if (i < 524288)  s = kw + (i - 262144);
  else if (i < 786432)  s = vw + (i - 524288);
  else if (i < 1048576) s = ow + (i - 786432);
  else if (i < 1114112) { s = pq + (i - 1048576); sc = g_q[0]; }
  else if (i < 1179648) { s = pk + (i - 1114112); sc = g_k[0]; }
  else                  { s = pv + (i - 1179648); sc = g_v2[0]; }
  fvec4 v = *(const fvec4*)s;
  bf16x4 o = { (bf16)(v[0] * sc), (bf16)(v[1] * sc),
               (bf16)(v[2] * sc), (bf16)(v[3] * sc) };
  *(bf16x4*)(dst + i) = o;
}

// ---------------------------------------------------------------------------
// Transpose/convert: x fp32 [b][c][h][w] -> xt bf16 [(lb*128+w)][512].
// ---------------------------------------------------------------------------
__global__ __launch_bounds__(256) void xpose_kernel(
    const float* __restrict__ x, bf16* __restrict__ xt, int bh0)
{
  __shared__ float Xs[64 * 133];
  const int cb = blockIdx.x, lb = blockIdx.y;
  const int bh = bh0 + lb, b = bh >> 7, h = bh & 127;
  const int t = threadIdx.x;
  const float* xb = x + (size_t)b * 8388608 + (size_t)(cb * 64) * 16384 + h * 128;
  #pragma unroll
  for (int it = 0; it < 8; ++it) {
    int idx = it * 256 + t;
    int c = idx >> 5, w4 = (idx & 31) << 2;
    fvec4 v = *(const fvec4*)(xb + (size_t)c * 16384 + w4);
    #pragma unroll
    for (int j = 0; j < 4; ++j) Xs[c * 133 + w4 + j] = v[j];
  }
  __syncthreads();
  const int c0 = (t & 7) * 8, wsub = t >> 3;
  #pragma unroll
  for (int wb = 0; wb < 4; ++wb) {
    int w = wb * 32 + wsub;
    bf16x8 o;
    #pragma unroll
    for (int i = 0; i < 8; ++i) o[i] = (bf16)Xs[(c0 + i) * 133 + w];
    *(bf16x8*)(xt + ((size_t)lb * 128 + w) * 512 + cb * 64 + c0) = o;
  }
}

// ---------------------------------------------------------------------------
// Fused QKV-GEMM + gated attention. One block = one (lb, head n).
// R5 vs R4:
//  - single-buffered BK=64 GEMM (m97 regime): LDS 48 KB -> 3 blocks/CU,
//    cross-block TLP hides barrier drain + attn VALU phases.
//  - gates pre-folded in prep: kc>=2 S-operand is a straight load; KP and
//    Vt epilogues lose their gate multiplies.
// LDS: GEMM As16K+Bs24K = 40 KB; attn overlay Qs16K @0 / KP32K @16K = 48 KB.
// ---------------------------------------------------------------------------
__global__ __launch_bounds__(512, 6) void qkvattn_kernel(
    const bf16* __restrict__ xt, const bf16* __restrict__ wqkv,
    const float* __restrict__ q_b, const float* __restrict__ k_b,
    const float* __restrict__ v_b, const bf16* __restrict__ posb,
    const float* __restrict__ g_v1, bf16* __restrict__ ao)
{
  __shared__ bf16 SM[24576];            // 49152 B
  // GEMM: As [128][64] @0, Bs [192][64] @8192
  // Attn overlay: Qs [128][64] @0, KP [128][128] @8192,
  //               Vt [64][128] @0 (aliases Qs after S-phase)
  bf16* Qs = SM;
  bf16* KP = SM + 8192;
  bf16* Vt = SM;

  const int nwg = gridDim.x;
  int wg = blockIdx.x;
  wg = (wg & 7) * (nwg >> 3) + (wg >> 3);     // nwg % 8 == 0 always
  const int lb = wg >> 3, n = wg & 7;

  const int t = threadIdx.x;
  const int wv = t >> 6, lane = t & 63;
  const int lr = lane & 15, lg = lane >> 4;
  const int srow = lane >> 3, c16 = lane & 7;
  const int wm2 = wv >> 1, wn2 = wv & 1;      // 4M x 2N wave grid

  // ---------------- Phase 1: GEMM [128 w][192 {q|k|v}] ----------------
  fvec4 acc[2][6];
  #pragma unroll
  for (int i = 0; i < 2; ++i)
    #pragma unroll
    for (int j = 0; j < 6; ++j) acc[i][j] = zero4();

  const bf16* asrc[2];
  const bf16* bsrc[3];
  #pragma unroll
  for (int j = 0; j < 2; ++j) {
    int seg = wv * 2 + j;
    int row = seg * 8 + srow;
    int cs = c16 ^ (row & 7);
    asrc[j] = xt + (size_t)(lb * 128 + row) * 512 + cs * 8;
  }
  #pragma unroll
  for (int j = 0; j < 3; ++j) {
    int seg = wv * 3 + j;
    int row = seg * 8 + srow;                      // 0..191 concat row
    int grow = ((row >> 6) << 9) + (n << 6) + (row & 63);  // wqkv row
    int cs = c16 ^ (row & 7);
    bsrc[j] = wqkv + (size_t)grow * 512 + cs * 8;
  }

  for (int k0 = 0; k0 < 512; k0 += 64) {
    __syncthreads();                     // protect As/Bs from prior reads
    #pragma unroll
    for (int j = 0; j < 2; ++j) glds16(asrc[j] + k0, SM + (wv * 2 + j) * 512);
    #pragma unroll
    for (int j = 0; j < 3; ++j) glds16(bsrc[j] + k0, SM + 8192 + (wv * 3 + j) * 512);
    __syncthreads();                     // vmcnt drained: tile ready
    #pragma unroll
    for (int kc = 0; kc < 2; ++kc) {
      bf16x8 af[2], bfv[6];
      #pragma unroll
      for (int mt = 0; mt < 2; ++mt) {
        int row = wm2 * 32 + mt * 16 + lr;
        int cs = (kc * 4 + lg) ^ (row & 7);
        af[mt] = *(const bf16x8*)(SM + row * 64 + cs * 8);
      }
      #pragma unroll
      for (int nt = 0; nt < 6; ++nt) {
        int row = wn2 * 96 + nt * 16 + lr;
        int cs = (kc * 4 + lg) ^ (row & 7);
        bfv[nt] = *(const bf16x8*)(SM + 8192 + row * 64 + cs * 8);
      }
      #pragma unroll
      for (int mt = 0; mt < 2; ++mt)
        #pragma unroll
        for (int nt = 0; nt < 6; ++nt)
          acc[mt][nt] = MFMA16(af[mt], bfv[nt], acc[mt][nt]);
    }
  }
  __syncthreads();   // all As/Bs reads done before overlay overwrite

  // ---------------- Phase 2: epilogue -> Qs, KP (V stays in regs) ----------
  const float gv1 = g_v1[0];
  const bf16* pqb = posb + (size_t)n * 8192;            // pre-scaled by gq
  const bf16* pkb = posb + 65536 + (size_t)n * 8192;    // pre-scaled by gk
  const bf16* pvb = posb + 131072 + (size_t)n * 8192;   // pre-scaled by gv2

  #pragma unroll
  for (int mt = 0; mt < 2; ++mt) {
    #pragma unroll
    for (int nt = 0; nt < 6; ++nt) {
      int gc = wn2 * 96 + nt * 16 + lr;   // 0..191 concat col (sec uniform/wave)
      int sec = gc >> 6;
      int d = gc & 63;
      int rb = wm2 * 32 + mt * 16 + lg * 4;
      if (sec == 0) {
        float bq = q_b[n * 64 + d];
        #pragma unroll
        for (int r = 0; r < 4; ++r) {
          int row = rb + r;
          Qs[row * 64 + (((d >> 3) ^ (row & 7)) << 3) + (d & 7)] =
              (bf16)(acc[mt][nt][r] + bq);
        }
      } else if (sec == 1) {
        float bk = k_b[n * 64 + d];
        #pragma unroll
        for (int r = 0; r < 4; ++r) {
          int row = rb + r;               // token j
          float kv = acc[mt][nt][r] + bk;
          KP[row * 128 + (((d >> 3) ^ (row & 7)) << 3) + (d & 7)] =
              (bf16)(kv + (float)pqb[row * 64 + d]);
          int d2 = 64 + d;
          KP[row * 128 + (((d2 >> 3) ^ (row & 7)) << 3) + (d2 & 7)] = (bf16)kv;
        }
      }
      // sec == 2: V kept in acc until after S-phase
    }
  }
  __syncthreads();

  // ---------------- Phase 3a: S = [q | pk'] @ KP^T ----------------
  const int i0 = wv * 16;
  fvec4 s[8];
  #pragma unroll
  for (int i = 0; i < 8; ++i) s[i] = zero4();
  #pragma unroll
  for (int kc = 0; kc < 4; ++kc) {
    bf16x8 af;
    if (kc < 2) {
      int row = i0 + lr;
      int cs = (kc * 4 + lg) ^ (row & 7);
      af = *(const bf16x8*)(Qs + row * 64 + cs * 8);
    } else {
      af = *(const bf16x8*)(pkb + (i0 + lr) * 64 + (kc - 2) * 32 + lg * 8);
    }
    #pragma unroll
    for (int jt = 0; jt < 8; ++jt) {
      int row = jt * 16 + lr;
      int cs = (kc * 4 + lg) ^ (row & 7);
      bf16x8 bfr = *(const bf16x8*)(KP + row * 128 + cs * 8);
      s[jt] = MFMA16(af, bfr, s[jt]);
    }
  }

  const float scale = 0.125f;
  float inv[4];
  #pragma unroll
  for (int r = 0; r < 4; ++r) {
    float m = -1e30f;
    #pragma unroll
    for (int jt = 0; jt < 8; ++jt) m = fmaxf(m, s[jt][r]);
    #pragma unroll
    for (int off = 1; off < 16; off <<= 1) m = fmaxf(m, __shfl_xor(m, off));
    float sm = 0.f;
    #pragma unroll
    for (int jt = 0; jt < 8; ++jt) {
      float e = __expf((s[jt][r] - m) * scale);
      s[jt][r] = e;
      sm += e;
    }
    #pragma unroll
    for (int off = 1; off < 16; off <<= 1) sm += __shfl_xor(sm, off);
    inv[r] = 1.f / sm;
  }
  __syncthreads();   // Qs + KP reads done

  // P -> KP (swizzled), Vmix^T -> Vt (Qs region, now dead)
  #pragma unroll
  for (int r = 0; r < 4; ++r) {
    int i = i0 + lg * 4 + r;
    #pragma unroll
    for (int jt = 0; jt < 8; ++jt) {
      int j = jt * 16 + lr;
      KP[i * 128 + (((j >> 3) ^ (i & 7)) << 3) + (j & 7)] =
          (bf16)(s[jt][r] * inv[r]);
    }
  }
  if (wn2 == 1) {
    #pragma unroll
    for (int mt = 0; mt < 2; ++mt) {
      #pragma unroll
      for (int nt = 2; nt < 6; ++nt) {
        int d = nt * 16 - 32 + lr;        // 0..63
        float bv = v_b[n * 64 + d];
        #pragma unroll
        for (int r = 0; r < 4; ++r) {
          int j = wm2 * 32 + mt * 16 + lg * 4 + r;   // token
          float vv = gv1 * (acc[mt][nt][r] + bv) + (float)pvb[j * 64 + d];
          Vt[d * 128 + (((j >> 3) ^ (d & 7)) << 3) + (j & 7)] = (bf16)vv;
        }
      }
    }
  }
  __syncthreads();

  // ---------------- Phase 3b: O = P @ Vmix ----------------
  fvec4 o[4];
  #pragma unroll
  for (int i = 0; i < 4; ++i) o[i] = zero4();
  #pragma unroll
  for (int kc = 0; kc < 4; ++kc) {
    int prow = i0 + lr;
    int pcs = (kc * 4 + lg) ^ (prow & 7);
    bf16x8 af = *(const bf16x8*)(KP + prow * 128 + pcs * 8);
    #pragma unroll
    for (int dt = 0; dt < 4; ++dt) {
      int vr = dt * 16 + lr;
      int vcs = (kc * 4 + lg) ^ (vr & 7);
      bf16x8 bfr = *(const bf16x8*)(Vt + vr * 128 + vcs * 8);
      o[dt] = MFMA16(af, bfr, o[dt]);
    }
  }
  #pragma unroll
  for (int dt = 0; dt < 4; ++dt) {
    #pragma unroll
    for (int r = 0; r < 4; ++r) {
      int i = i0 + lg * 4 + r;
      ao[((size_t)lb * 128 + i) * 512 + n * 64 + dt * 16 + lr] = (bf16)o[dt][r];
    }
  }
}

// ---------------------------------------------------------------------------
// O-proj GEMM: A = wo (m=co), B = ao rows (n=w). Epilogue adds o_b,
// writes out[b][co][h][w]. 1D grid + XCD swizzle. (unchanged this round)
// ---------------------------------------------------------------------------
__global__ __launch_bounds__(256, 3) void oproj_kernel(
    const bf16* __restrict__ ao, const bf16* __restrict__ wo,
    const float* __restrict__ o_b, float* __restrict__ out, int bh0)
{
  __shared__ bf16 As[128 * 64];
  __shared__ bf16 Bs[128 * 64];
  const int nwg = gridDim.x;
  int wg = blockIdx.x;
  if ((nwg & 7) == 0) wg = (wg & 7) * (nwg >> 3) + (wg >> 3);
  const int ct4 = wg & 3;                    // co tile (0..3)
  const int lb = wg >> 2;
  const int bh = bh0 + lb, b = bh >> 7, h = bh & 127;
  const int t = threadIdx.x;
  const int wv = t >> 6, lane = t & 63;
  const int lr = lane & 15, lg = lane >> 4;
  const int wm = wv >> 1, wn = wv & 1;
  const int srow = lane >> 3, c16 = lane & 7;

  fvec4 acc[4][4];
  #pragma unroll
  for (int i = 0; i < 4; ++i)
    #pragma unroll
    for (int j = 0; j < 4; ++j) acc[i][j] = zero4();

  for (int k0 = 0; k0 < 512; k0 += 64) {
    __syncthreads();
    #pragma unroll
    for (int j = 0; j < 4; ++j) {
      int seg = wv * 4 + j;
      int row = seg * 8 + srow;
      int cs = c16 ^ (row & 7);
      glds16(wo + (size_t)(ct4 * 128 + row) * 512 + k0 + cs * 8, As + seg * 512);
      glds16(ao + ((size_t)lb * 128 + row) * 512 + k0 + cs * 8, Bs + seg * 512);
    }
    __syncthreads();
    #pragma unroll
    for (int kc = 0; kc < 2; ++kc) {
      bf16x8 af[4], bfv[4];
      #pragma unroll
      for (int mt = 0; mt < 4; ++mt) {
        int row = wm * 64 + mt * 16 + lr;
        int cs = (kc * 4 + lg) ^ (row & 7);
        af[mt] = *(const bf16x8*)(As + row * 64 + cs * 8);
      }
      #pragma unroll
      for (int nt = 0; nt < 4; ++nt) {
        int row = wn * 64 + nt * 16 + lr;
        int cs = (kc * 4 + lg) ^ (row & 7);
        bfv[nt] = *(const bf16x8*)(Bs + row * 64 + cs * 8);
      }
      #pragma unroll
      for (int mt = 0; mt < 4; ++mt)
        #pragma unroll
        for (int nt = 0; nt < 4; ++nt)
          acc[mt][nt] = MFMA16(af[mt], bfv[nt], acc[mt][nt]);
    }
  }
  #pragma unroll
  for (int mt = 0; mt < 4; ++mt) {
    #pragma unroll
    for (int r = 0; r < 4; ++r) {
      int co = ct4 * 128 + wm * 64 + mt * 16 + lg * 4 + r;
      float bv = o_b[co];
      size_t ob = ((size_t)(b * 512 + co) * 128 + h) * 128;
      #pragma unroll
      for (int nt = 0; nt < 4; ++nt) {
        int w = wn * 64 + nt * 16 + lr;
        out[ob + w] = acc[mt][nt][r] + bv;
      }
    }
  }
}

// ---------------------------------------------------------------------------
extern "C" void kernel_launch(void* const* d_in, const int* in_sizes, int n_in,
                              void* d_out, int out_size, void* d_ws, size_t ws_size,
                              hipStream_t stream) {
  const float* x    = (const float*)d_in[0];
  const float* q_w  = (const float*)d_in[1];
  const float* q_b  = (const float*)d_in[2];
  const float* k_w  = (const float*)d_in[3];
  const float* k_b  = (const float*)d_in[4];
  const float* v_w  = (const float*)d_in[5];
  const float* v_b  = (const float*)d_in[6];
  const float* o_w  = (const float*)d_in[7];
  const float* o_b  = (const float*)d_in[8];
  const float* pos_q = (const float*)d_in[9];
  const float* pos_k = (const float*)d_in[10];
  const float* pos_v = (const float*)d_in[11];
  const float* g_q  = (const float*)d_in[12];
  const float* g_k  = (const float*)d_in[13];
  const float* g_v1 = (const float*)d_in[14];
  const float* g_v2 = (const float*)d_in[15];
  float* out = (float*)d_out;

  bf16* prep = (bf16*)d_ws;
  bf16* wqkv = prep;                       // 786432
  bf16* wo   = prep + 786432;              // 262144
  bf16* posb = prep + 1048576;             // 196608

  bf16* rest = prep + PREP_ELEMS;
  size_t avail = (ws_size > (size_t)PREP_ELEMS * 2) ? ws_size - (size_t)PREP_ELEMS * 2 : 0;
  // per bh: xt (128*512) + ao (128*512), bf16 -> 256 KB
  const size_t per_bh = (size_t)(65536 + 65536) * sizeof(bf16);
  int nbh = (int)(avail / per_bh);
  if (nbh > 512) nbh = 512;
  if (nbh < 1) nbh = 1;

  bf16* xt = rest;                                  // nbh*65536
  bf16* ao = xt + (size_t)nbh * 65536;              // nbh*65536

  prep_kernel<<<608, 512, 0, stream>>>(q_w, k_w, v_w, o_w, pos_q, pos_k, pos_v,
                                       g_q, g_k, g_v2, prep);

  for (int bh0 = 0; bh0 < 512; bh0 += nbh) {
    int cur = (512 - bh0 < nbh) ? (512 - bh0) : nbh;
    xpose_kernel<<<dim3(8, cur), 256, 0, stream>>>(x, xt, bh0);
    qkvattn_kernel<<<cur * 8, 512, 0, stream>>>(xt, wqkv, q_b, k_b, v_b, posb,
                                                g_v1, ao);
    oproj_kernel<<<cur * 4, 256, 0, stream>>>(ao, wo, o_b, out, bh0);
  }
}

// Round 6
// 504.154 us; speedup vs baseline: 1.3770x; 1.3770x over previous
//
#include <hip/hip_runtime.h>

typedef __bf16 bf16;
typedef __attribute__((ext_vector_type(8))) __bf16 bf16x8;
typedef __attribute__((ext_vector_type(4))) __bf16 bf16x4;
typedef __attribute__((ext_vector_type(4))) float fvec4;

#define MFMA16(a, b, c) __builtin_amdgcn_mfma_f32_16x16x32_bf16(a, b, c, 0, 0, 0)

__device__ __forceinline__ void glds16(const bf16* g, bf16* l) {
  __builtin_amdgcn_global_load_lds(
      (const __attribute__((address_space(1))) void*)g,
      (__attribute__((address_space(3))) void*)l, 16, 0, 0);
}

__device__ inline fvec4 zero4() { fvec4 z = {0.f, 0.f, 0.f, 0.f}; return z; }

// Workspace bf16 layout (elements):
//   wqkv : [1536][512] q/k/v rows contiguous @ 0        (786432)
//   wo   : [512][512]                        @ 786432   (262144)
//   posb : pq*gq / pk*gk / pv*gv2 [8][128][64] @ 1048576 (196608)
#define PREP_ELEMS 1245184

// Gates folded here (pq *= g_q, pk *= g_k, pv *= g_v2) so the hot
// kernel does straight loads/adds.
__global__ __launch_bounds__(512) void prep_kernel(
    const float* __restrict__ qw, const float* __restrict__ kw,
    const float* __restrict__ vw, const float* __restrict__ ow,
    const float* __restrict__ pq, const float* __restrict__ pk,
    const float* __restrict__ pv,
    const float* __restrict__ g_q, const float* __restrict__ g_k,
    const float* __restrict__ g_v2, bf16* __restrict__ dst)
{
  int i = (blockIdx.x * 512 + threadIdx.x) * 4;
  const float* s;
  float sc = 1.f;
  if      (i < 262144)  s = qw + i;
  else if (i < 524288)  s = kw + (i - 262144);
  else if (i < 786432)  s = vw + (i - 524288);
  else if (i < 1048576) s = ow + (i - 786432);
  else if (i < 1114112) { s = pq + (i - 1048576); sc = g_q[0]; }
  else if (i < 1179648) { s = pk + (i - 1114112); sc = g_k[0]; }
  else                  { s = pv + (i - 1179648); sc = g_v2[0]; }
  fvec4 v = *(const fvec4*)s;
  bf16x4 o = { (bf16)(v[0] * sc), (bf16)(v[1] * sc),
               (bf16)(v[2] * sc), (bf16)(v[3] * sc) };
  *(bf16x4*)(dst + i) = o;
}

// ---------------------------------------------------------------------------
// Transpose/convert: x fp32 [b][c][h][w] -> xt bf16 [(lb*128+w)][512].
// ---------------------------------------------------------------------------
__global__ __launch_bounds__(256) void xpose_kernel(
    const float* __restrict__ x, bf16* __restrict__ xt, int bh0)
{
  __shared__ float Xs[64 * 133];
  const int cb = blockIdx.x, lb = blockIdx.y;
  const int bh = bh0 + lb, b = bh >> 7, h = bh & 127;
  const int t = threadIdx.x;
  const float* xb = x + (size_t)b * 8388608 + (size_t)(cb * 64) * 16384 + h * 128;
  #pragma unroll
  for (int it = 0; it < 8; ++it) {
    int idx = it * 256 + t;
    int c = idx >> 5, w4 = (idx & 31) << 2;
    fvec4 v = *(const fvec4*)(xb + (size_t)c * 16384 + w4);
    #pragma unroll
    for (int j = 0; j < 4; ++j) Xs[c * 133 + w4 + j] = v[j];
  }
  __syncthreads();
  const int c0 = (t & 7) * 8, wsub = t >> 3;
  #pragma unroll
  for (int wb = 0; wb < 4; ++wb) {
    int w = wb * 32 + wsub;
    bf16x8 o;
    #pragma unroll
    for (int i = 0; i < 8; ++i) o[i] = (bf16)Xs[(c0 + i) * 133 + w];
    *(bf16x8*)(xt + ((size_t)lb * 128 + w) * 512 + cb * 64 + c0) = o;
  }
}

// ---------------------------------------------------------------------------
// Fused QKV-GEMM + gated attention. One block = one (lb, head n).
// R6 vs R5: __launch_bounds__(512,4) -- R5's (512,6) forced VGPR cap 64
// (incl. unified AGPRs), spilling accumulators to scratch (628 MB phantom
// writes, VGPR=40, 397 us). At cap 128 the kernel fits in ~60 VGPR (R4
// evidence), and 48 KB LDS still yields 3 blocks/CU (144 KB < 160 KB).
// LDS: GEMM As16K+Bs24K = 40 KB; attn overlay Qs16K @0 / KP32K @16K = 48 KB.
// ---------------------------------------------------------------------------
__global__ __launch_bounds__(512, 4) void qkvattn_kernel(
    const bf16* __restrict__ xt, const bf16* __restrict__ wqkv,
    const float* __restrict__ q_b, const float* __restrict__ k_b,
    const float* __restrict__ v_b, const bf16* __restrict__ posb,
    const float* __restrict__ g_v1, bf16* __restrict__ ao)
{
  __shared__ bf16 SM[24576];            // 49152 B
  // GEMM: As [128][64] @0, Bs [192][64] @8192
  // Attn overlay: Qs [128][64] @0, KP [128][128] @8192,
  //               Vt [64][128] @0 (aliases Qs after S-phase)
  bf16* Qs = SM;
  bf16* KP = SM + 8192;
  bf16* Vt = SM;

  const int nwg = gridDim.x;
  int wg = blockIdx.x;
  wg = (wg & 7) * (nwg >> 3) + (wg >> 3);     // nwg % 8 == 0 always
  const int lb = wg >> 3, n = wg & 7;

  const int t = threadIdx.x;
  const int wv = t >> 6, lane = t & 63;
  const int lr = lane & 15, lg = lane >> 4;
  const int srow = lane >> 3, c16 = lane & 7;
  const int wm2 = wv >> 1, wn2 = wv & 1;      // 4M x 2N wave grid

  // ---------------- Phase 1: GEMM [128 w][192 {q|k|v}] ----------------
  fvec4 acc[2][6];
  #pragma unroll
  for (int i = 0; i < 2; ++i)
    #pragma unroll
    for (int j = 0; j < 6; ++j) acc[i][j] = zero4();

  const bf16* asrc[2];
  const bf16* bsrc[3];
  #pragma unroll
  for (int j = 0; j < 2; ++j) {
    int seg = wv * 2 + j;
    int row = seg * 8 + srow;
    int cs = c16 ^ (row & 7);
    asrc[j] = xt + (size_t)(lb * 128 + row) * 512 + cs * 8;
  }
  #pragma unroll
  for (int j = 0; j < 3; ++j) {
    int seg = wv * 3 + j;
    int row = seg * 8 + srow;                      // 0..191 concat row
    int grow = ((row >> 6) << 9) + (n << 6) + (row & 63);  // wqkv row
    int cs = c16 ^ (row & 7);
    bsrc[j] = wqkv + (size_t)grow * 512 + cs * 8;
  }

  for (int k0 = 0; k0 < 512; k0 += 64) {
    __syncthreads();                     // protect As/Bs from prior reads
    #pragma unroll
    for (int j = 0; j < 2; ++j) glds16(asrc[j] + k0, SM + (wv * 2 + j) * 512);
    #pragma unroll
    for (int j = 0; j < 3; ++j) glds16(bsrc[j] + k0, SM + 8192 + (wv * 3 + j) * 512);
    __syncthreads();                     // vmcnt drained: tile ready
    #pragma unroll
    for (int kc = 0; kc < 2; ++kc) {
      bf16x8 af[2], bfv[6];
      #pragma unroll
      for (int mt = 0; mt < 2; ++mt) {
        int row = wm2 * 32 + mt * 16 + lr;
        int cs = (kc * 4 + lg) ^ (row & 7);
        af[mt] = *(const bf16x8*)(SM + row * 64 + cs * 8);
      }
      #pragma unroll
      for (int nt = 0; nt < 6; ++nt) {
        int row = wn2 * 96 + nt * 16 + lr;
        int cs = (kc * 4 + lg) ^ (row & 7);
        bfv[nt] = *(const bf16x8*)(SM + 8192 + row * 64 + cs * 8);
      }
      #pragma unroll
      for (int mt = 0; mt < 2; ++mt)
        #pragma unroll
        for (int nt = 0; nt < 6; ++nt)
          acc[mt][nt] = MFMA16(af[mt], bfv[nt], acc[mt][nt]);
    }
  }
  __syncthreads();   // all As/Bs reads done before overlay overwrite

  // ---------------- Phase 2: epilogue -> Qs, KP (V stays in regs) ----------
  const float gv1 = g_v1[0];
  const bf16* pqb = posb + (size_t)n * 8192;            // pre-scaled by gq
  const bf16* pkb = posb + 65536 + (size_t)n * 8192;    // pre-scaled by gk
  const bf16* pvb = posb + 131072 + (size_t)n * 8192;   // pre-scaled by gv2

  #pragma unroll
  for (int mt = 0; mt < 2; ++mt) {
    #pragma unroll
    for (int nt = 0; nt < 6; ++nt) {
      int gc = wn2 * 96 + nt * 16 + lr;   // 0..191 concat col (sec uniform/wave)
      int sec = gc >> 6;
      int d = gc & 63;
      int rb = wm2 * 32 + mt * 16 + lg * 4;
      if (sec == 0) {
        float bq = q_b[n * 64 + d];
        #pragma unroll
        for (int r = 0; r < 4; ++r) {
          int row = rb + r;
          Qs[row * 64 + (((d >> 3) ^ (row & 7)) << 3) + (d & 7)] =
              (bf16)(acc[mt][nt][r] + bq);
        }
      } else if (sec == 1) {
        float bk = k_b[n * 64 + d];
        #pragma unroll
        for (int r = 0; r < 4; ++r) {
          int row = rb + r;               // token j
          float kv = acc[mt][nt][r] + bk;
          KP[row * 128 + (((d >> 3) ^ (row & 7)) << 3) + (d & 7)] =
              (bf16)(kv + (float)pqb[row * 64 + d]);
          int d2 = 64 + d;
          KP[row * 128 + (((d2 >> 3) ^ (row & 7)) << 3) + (d2 & 7)] = (bf16)kv;
        }
      }
      // sec == 2: V kept in acc until after S-phase
    }
  }
  __syncthreads();

  // ---------------- Phase 3a: S = [q | pk'] @ KP^T ----------------
  const int i0 = wv * 16;
  fvec4 s[8];
  #pragma unroll
  for (int i = 0; i < 8; ++i) s[i] = zero4();
  #pragma unroll
  for (int kc = 0; kc < 4; ++kc) {
    bf16x8 af;
    if (kc < 2) {
      int row = i0 + lr;
      int cs = (kc * 4 + lg) ^ (row & 7);
      af = *(const bf16x8*)(Qs + row * 64 + cs * 8);
    } else {
      af = *(const bf16x8*)(pkb + (i0 + lr) * 64 + (kc - 2) * 32 + lg * 8);
    }
    #pragma unroll
    for (int jt = 0; jt < 8; ++jt) {
      int row = jt * 16 + lr;
      int cs = (kc * 4 + lg) ^ (row & 7);
      bf16x8 bfr = *(const bf16x8*)(KP + row * 128 + cs * 8);
      s[jt] = MFMA16(af, bfr, s[jt]);
    }
  }

  const float scale = 0.125f;
  float inv[4];
  #pragma unroll
  for (int r = 0; r < 4; ++r) {
    float m = -1e30f;
    #pragma unroll
    for (int jt = 0; jt < 8; ++jt) m = fmaxf(m, s[jt][r]);
    #pragma unroll
    for (int off = 1; off < 16; off <<= 1) m = fmaxf(m, __shfl_xor(m, off));
    float sm = 0.f;
    #pragma unroll
    for (int jt = 0; jt < 8; ++jt) {
      float e = __expf((s[jt][r] - m) * scale);
      s[jt][r] = e;
      sm += e;
    }
    #pragma unroll
    for (int off = 1; off < 16; off <<= 1) sm += __shfl_xor(sm, off);
    inv[r] = 1.f / sm;
  }
  __syncthreads();   // Qs + KP reads done

  // P -> KP (swizzled), Vmix^T -> Vt (Qs region, now dead)
  #pragma unroll
  for (int r = 0; r < 4; ++r) {
    int i = i0 + lg * 4 + r;
    #pragma unroll
    for (int jt = 0; jt < 8; ++jt) {
      int j = jt * 16 + lr;
      KP[i * 128 + (((j >> 3) ^ (i & 7)) << 3) + (j & 7)] =
          (bf16)(s[jt][r] * inv[r]);
    }
  }
  if (wn2 == 1) {
    #pragma unroll
    for (int mt = 0; mt < 2; ++mt) {
      #pragma unroll
      for (int nt = 2; nt < 6; ++nt) {
        int d = nt * 16 - 32 + lr;        // 0..63
        float bv = v_b[n * 64 + d];
        #pragma unroll
        for (int r = 0; r < 4; ++r) {
          int j = wm2 * 32 + mt * 16 + lg * 4 + r;   // token
          float vv = gv1 * (acc[mt][nt][r] + bv) + (float)pvb[j * 64 + d];
          Vt[d * 128 + (((j >> 3) ^ (d & 7)) << 3) + (j & 7)] = (bf16)vv;
        }
      }
    }
  }
  __syncthreads();

  // ---------------- Phase 3b: O = P @ Vmix ----------------
  fvec4 o[4];
  #pragma unroll
  for (int i = 0; i < 4; ++i) o[i] = zero4();
  #pragma unroll
  for (int kc = 0; kc < 4; ++kc) {
    int prow = i0 + lr;
    int pcs = (kc * 4 + lg) ^ (prow & 7);
    bf16x8 af = *(const bf16x8*)(KP + prow * 128 + pcs * 8);
    #pragma unroll
    for (int dt = 0; dt < 4; ++dt) {
      int vr = dt * 16 + lr;
      int vcs = (kc * 4 + lg) ^ (vr & 7);
      bf16x8 bfr = *(const bf16x8*)(Vt + vr * 128 + vcs * 8);
      o[dt] = MFMA16(af, bfr, o[dt]);
    }
  }
  #pragma unroll
  for (int dt = 0; dt < 4; ++dt) {
    #pragma unroll
    for (int r = 0; r < 4; ++r) {
      int i = i0 + lg * 4 + r;
      ao[((size_t)lb * 128 + i) * 512 + n * 64 + dt * 16 + lr] = (bf16)o[dt][r];
    }
  }
}

// ---------------------------------------------------------------------------
// O-proj GEMM: A = wo (m=co), B = ao rows (n=w). Epilogue adds o_b,
// writes out[b][co][h][w]. 1D grid + XCD swizzle. (unchanged this round)
// ---------------------------------------------------------------------------
__global__ __launch_bounds__(256, 3) void oproj_kernel(
    const bf16* __restrict__ ao, const bf16* __restrict__ wo,
    const float* __restrict__ o_b, float* __restrict__ out, int bh0)
{
  __shared__ bf16 As[128 * 64];
  __shared__ bf16 Bs[128 * 64];
  const int nwg = gridDim.x;
  int wg = blockIdx.x;
  if ((nwg & 7) == 0) wg = (wg & 7) * (nwg >> 3) + (wg >> 3);
  const int ct4 = wg & 3;                    // co tile (0..3)
  const int lb = wg >> 2;
  const int bh = bh0 + lb, b = bh >> 7, h = bh & 127;
  const int t = threadIdx.x;
  const int wv = t >> 6, lane = t & 63;
  const int lr = lane & 15, lg = lane >> 4;
  const int wm = wv >> 1, wn = wv & 1;
  const int srow = lane >> 3, c16 = lane & 7;

  fvec4 acc[4][4];
  #pragma unroll
  for (int i = 0; i < 4; ++i)
    #pragma unroll
    for (int j = 0; j < 4; ++j) acc[i][j] = zero4();

  for (int k0 = 0; k0 < 512; k0 += 64) {
    __syncthreads();
    #pragma unroll
    for (int j = 0; j < 4; ++j) {
      int seg = wv * 4 + j;
      int row = seg * 8 + srow;
      int cs = c16 ^ (row & 7);
      glds16(wo + (size_t)(ct4 * 128 + row) * 512 + k0 + cs * 8, As + seg * 512);
      glds16(ao + ((size_t)lb * 128 + row) * 512 + k0 + cs * 8, Bs + seg * 512);
    }
    __syncthreads();
    #pragma unroll
    for (int kc = 0; kc < 2; ++kc) {
      bf16x8 af[4], bfv[4];
      #pragma unroll
      for (int mt = 0; mt < 4; ++mt) {
        int row = wm * 64 + mt * 16 + lr;
        int cs = (kc * 4 + lg) ^ (row & 7);
        af[mt] = *(const bf16x8*)(As + row * 64 + cs * 8);
      }
      #pragma unroll
      for (int nt = 0; nt < 4; ++nt) {
        int row = wn * 64 + nt * 16 + lr;
        int cs = (kc * 4 + lg) ^ (row & 7);
        bfv[nt] = *(const bf16x8*)(Bs + row * 64 + cs * 8);
      }
      #pragma unroll
      for (int mt = 0; mt < 4; ++mt)
        #pragma unroll
        for (int nt = 0; nt < 4; ++nt)
          acc[mt][nt] = MFMA16(af[mt], bfv[nt], acc[mt][nt]);
    }
  }
  #pragma unroll
  for (int mt = 0; mt < 4; ++mt) {
    #pragma unroll
    for (int r = 0; r < 4; ++r) {
      int co = ct4 * 128 + wm * 64 + mt * 16 + lg * 4 + r;
      float bv = o_b[co];
      size_t ob = ((size_t)(b * 512 + co) * 128 + h) * 128;
      #pragma unroll
      for (int nt = 0; nt < 4; ++nt) {
        int w = wn * 64 + nt * 16 + lr;
        out[ob + w] = acc[mt][nt][r] + bv;
      }
    }
  }
}

// ---------------------------------------------------------------------------
extern "C" void kernel_launch(void* const* d_in, const int* in_sizes, int n_in,
                              void* d_out, int out_size, void* d_ws, size_t ws_size,
                              hipStream_t stream) {
  const float* x    = (const float*)d_in[0];
  const float* q_w  = (const float*)d_in[1];
  const float* q_b  = (const float*)d_in[2];
  const float* k_w  = (const float*)d_in[3];
  const float* k_b  = (const float*)d_in[4];
  const float* v_w  = (const float*)d_in[5];
  const float* v_b  = (const float*)d_in[6];
  const float* o_w  = (const float*)d_in[7];
  const float* o_b  = (const float*)d_in[8];
  const float* pos_q = (const float*)d_in[9];
  const float* pos_k = (const float*)d_in[10];
  const float* pos_v = (const float*)d_in[11];
  const float* g_q  = (const float*)d_in[12];
  const float* g_k  = (const float*)d_in[13];
  const float* g_v1 = (const float*)d_in[14];
  const float* g_v2 = (const float*)d_in[15];
  float* out = (float*)d_out;

  bf16* prep = (bf16*)d_ws;
  bf16* wqkv = prep;                       // 786432
  bf16* wo   = prep + 786432;              // 262144
  bf16* posb = prep + 1048576;             // 196608

  bf16* rest = prep + PREP_ELEMS;
  size_t avail = (ws_size > (size_t)PREP_ELEMS * 2) ? ws_size - (size_t)PREP_ELEMS * 2 : 0;
  // per bh: xt (128*512) + ao (128*512), bf16 -> 256 KB
  const size_t per_bh = (size_t)(65536 + 65536) * sizeof(bf16);
  int nbh = (int)(avail / per_bh);
  if (nbh > 512) nbh = 512;
  if (nbh < 1) nbh = 1;

  bf16* xt = rest;                                  // nbh*65536
  bf16* ao = xt + (size_t)nbh * 65536;              // nbh*65536

  prep_kernel<<<608, 512, 0, stream>>>(q_w, k_w, v_w, o_w, pos_q, pos_k, pos_v,
                                       g_q, g_k, g_v2, prep);

  for (int bh0 = 0; bh0 < 512; bh0 += nbh) {
    int cur = (512 - bh0 < nbh) ? (512 - bh0) : nbh;
    xpose_kernel<<<dim3(8, cur), 256, 0, stream>>>(x, xt, bh0);
    qkvattn_kernel<<<cur * 8, 512, 0, stream>>>(xt, wqkv, q_b, k_b, v_b, posb,
                                                g_v1, ao);
    oproj_kernel<<<cur * 4, 256, 0, stream>>>(ao, wo, o_b, out, bh0);
  }
}

// Round 7
// 482.944 us; speedup vs baseline: 1.4374x; 1.0439x over previous
//
#include <hip/hip_runtime.h>

typedef __bf16 bf16;
typedef __attribute__((ext_vector_type(8))) __bf16 bf16x8;
typedef __attribute__((ext_vector_type(4))) __bf16 bf16x4;
typedef __attribute__((ext_vector_type(4))) float fvec4;

#define MFMA16(a, b, c) __builtin_amdgcn_mfma_f32_16x16x32_bf16(a, b, c, 0, 0, 0)

__device__ __forceinline__ void glds16(const bf16* g, bf16* l) {
  __builtin_amdgcn_global_load_lds(
      (const __attribute__((address_space(1))) void*)g,
      (__attribute__((address_space(3))) void*)l, 16, 0, 0);
}

__device__ inline fvec4 zero4() { fvec4 z = {0.f, 0.f, 0.f, 0.f}; return z; }

// Workspace bf16 layout (elements):
//   wqkv : [1536][512] q/k/v rows contiguous @ 0        (786432)
//   wo   : [512][512]                        @ 786432   (262144)
//   posb : pq*gq / pk*gk / pv*gv2 [8][128][64] @ 1048576 (196608)
#define PREP_ELEMS 1245184

// Gates folded here (pq *= g_q, pk *= g_k, pv *= g_v2).
__global__ __launch_bounds__(512) void prep_kernel(
    const float* __restrict__ qw, const float* __restrict__ kw,
    const float* __restrict__ vw, const float* __restrict__ ow,
    const float* __restrict__ pq, const float* __restrict__ pk,
    const float* __restrict__ pv,
    const float* __restrict__ g_q, const float* __restrict__ g_k,
    const float* __restrict__ g_v2, bf16* __restrict__ dst)
{
  int i = (blockIdx.x * 512 + threadIdx.x) * 4;
  const float* s;
  float sc = 1.f;
  if      (i < 262144)  s = qw + i;
  else if (i < 524288)  s = kw + (i - 262144);
  else if (i < 786432)  s = vw + (i - 524288);
  else if (i < 1048576) s = ow + (i - 786432);
  else if (i < 1114112) { s = pq + (i - 1048576); sc = g_q[0]; }
  else if (i < 1179648) { s = pk + (i - 1114112); sc = g_k[0]; }
  else                  { s = pv + (i - 1179648); sc = g_v2[0]; }
  fvec4 v = *(const fvec4*)s;
  bf16x4 o = { (bf16)(v[0] * sc), (bf16)(v[1] * sc),
               (bf16)(v[2] * sc), (bf16)(v[3] * sc) };
  *(bf16x4*)(dst + i) = o;
}

// ---------------------------------------------------------------------------
// Fused transpose + QKV-GEMM + gated attention. One block = one (bh, head n).
// R7 vs R4/R6:
//  - dbuf GEMM restored (R4: 186.5us beat R6 single-buf 193.2; occupancy
//    counter showed 3 blocks/CU never materialized at 48KB).
//  - xpose_kernel ELIMINATED: A-tile staged directly from x fp32 with an
//    in-register transpose (T14 async-STAGE split):
//      per K-step/thread: 16 coalesced global_load_dword (lanes span w),
//      issued top-of-step -> land under MFMA; cvt+2x ds_write_b128 along c
//      (XOR octet^(w&7), b128 bank floor) after compute, published by the
//      single per-step barrier into the dead dbuf half.
//  - B path unchanged: 3x glds16 with pre-swizzled global source.
// LDS: 2 x (As[128][64] 16K + Bs[192][64] 24K) = 80KB; attn overlay
//      Qs 16K @0 / KP 32K @16K / Vt aliases Qs. 2 blocks/CU.
// ---------------------------------------------------------------------------
__global__ __launch_bounds__(512, 4) void qkvattn_kernel(
    const float* __restrict__ x, const bf16* __restrict__ wqkv,
    const float* __restrict__ q_b, const float* __restrict__ k_b,
    const float* __restrict__ v_b, const bf16* __restrict__ posb,
    const float* __restrict__ g_v1, bf16* __restrict__ ao, int bh0)
{
  __shared__ bf16 SM[40960];            // 81920 B; buf b @ b*20480
  bf16* Qs = SM;                        // [128][64]  (after GEMM)
  bf16* KP = SM + 8192;                 // [128][128]
  bf16* Vt = SM;                        // [64][128] (after S, aliases Qs)

  const int nwg = gridDim.x;
  int wg = blockIdx.x;
  wg = (wg & 7) * (nwg >> 3) + (wg >> 3);     // nwg % 8 == 0 always
  const int lb = wg >> 3, n = wg & 7;
  const int bh = bh0 + lb, bb = bh >> 7, hh = bh & 127;

  const int t = threadIdx.x;
  const int wv = t >> 6, lane = t & 63;
  const int lr = lane & 15, lg = lane >> 4;
  const int srow = lane >> 3, c16 = lane & 7;
  const int wm2 = wv >> 1, wn2 = wv & 1;      // 4M x 2N wave grid

  // ---------------- Phase 1: GEMM [128 w][192 {q|k|v}], K=512 -------------
  fvec4 acc[2][6];
  #pragma unroll
  for (int i = 0; i < 2; ++i)
    #pragma unroll
    for (int j = 0; j < 6; ++j) acc[i][j] = zero4();

  // A-stage ownership: w in {wl, wl+64}, c-octet at ac0 = (t>>6)*8
  const int wl = t & 63, ac0 = (t >> 6) << 3;
  const float* xA = x + (size_t)bb * 8388608 + (size_t)ac0 * 16384 + hh * 128;
  float ar[16];

  const bf16* bsrc[3];
  #pragma unroll
  for (int j = 0; j < 3; ++j) {
    int seg = wv * 3 + j;
    int row = seg * 8 + srow;                      // 0..191 concat row
    int grow = ((row >> 6) << 9) + (n << 6) + (row & 63);  // wqkv row
    int cs = c16 ^ (row & 7);
    bsrc[j] = wqkv + (size_t)grow * 512 + cs * 8;
  }

#define LOADA(k0)                                                   \
  {                                                                 \
    const float* p = xA + (size_t)(k0) * 16384;                     \
    _Pragma("unroll")                                               \
    for (int i = 0; i < 8; ++i) {                                   \
      ar[i]     = p[(size_t)i * 16384 + wl];                        \
      ar[8 + i] = p[(size_t)i * 16384 + wl + 64];                   \
    }                                                               \
  }
#define WRITEA(Ad)                                                  \
  {                                                                 \
    _Pragma("unroll")                                               \
    for (int g = 0; g < 2; ++g) {                                   \
      int w = wl + g * 64;                                          \
      bf16x8 v;                                                     \
      _Pragma("unroll")                                             \
      for (int i = 0; i < 8; ++i) v[i] = (bf16)ar[g * 8 + i];       \
      int oc = (ac0 >> 3) ^ (w & 7);                                \
      *(bf16x8*)((Ad) + w * 64 + oc * 8) = v;                       \
    }                                                               \
  }

  // prologue: tile 0 into buf 0
  LOADA(0);
  #pragma unroll
  for (int j = 0; j < 3; ++j) glds16(bsrc[j], SM + 8192 + (wv * 3 + j) * 512);
  WRITEA(SM);
  __syncthreads();                       // publish buf0 (A writes + B glds16)

  int cur = 0;
  for (int k0 = 0; k0 < 512; k0 += 64) {
    bf16* nb = SM + (cur ^ 1) * 20480;   // dead buffer
    if (k0 < 448) {
      LOADA(k0 + 64);                    // in flight under compute
      #pragma unroll
      for (int j = 0; j < 3; ++j)
        glds16(bsrc[j] + k0 + 64, nb + 8192 + (wv * 3 + j) * 512);
    }
    const bf16* Ab = SM + cur * 20480;
    const bf16* Bb = Ab + 8192;
    #pragma unroll
    for (int kc = 0; kc < 2; ++kc) {
      bf16x8 af[2], bfv[6];
      #pragma unroll
      for (int mt = 0; mt < 2; ++mt) {
        int row = wm2 * 32 + mt * 16 + lr;
        int cs = (kc * 4 + lg) ^ (row & 7);
        af[mt] = *(const bf16x8*)(Ab + row * 64 + cs * 8);
      }
      #pragma unroll
      for (int nt = 0; nt < 6; ++nt) {
        int row = wn2 * 96 + nt * 16 + lr;
        int cs = (kc * 4 + lg) ^ (row & 7);
        bfv[nt] = *(const bf16x8*)(Bb + row * 64 + cs * 8);
      }
      #pragma unroll
      for (int mt = 0; mt < 2; ++mt)
        #pragma unroll
        for (int nt = 0; nt < 6; ++nt)
          acc[mt][nt] = MFMA16(af[mt], bfv[nt], acc[mt][nt]);
    }
    if (k0 < 448) WRITEA(nb);            // cvt + LDS write after compute
    __syncthreads();                     // publish nb; retire reads of cur
    cur ^= 1;
  }
#undef LOADA
#undef WRITEA

  // ---------------- Phase 2: epilogue -> Qs, KP (V stays in regs) ----------
  const float gv1 = g_v1[0];
  const bf16* pqb = posb + (size_t)n * 8192;            // pre-scaled by gq
  const bf16* pkb = posb + 65536 + (size_t)n * 8192;    // pre-scaled by gk
  const bf16* pvb = posb + 131072 + (size_t)n * 8192;   // pre-scaled by gv2

  #pragma unroll
  for (int mt = 0; mt < 2; ++mt) {
    #pragma unroll
    for (int nt = 0; nt < 6; ++nt) {
      int gc = wn2 * 96 + nt * 16 + lr;   // 0..191 concat col (sec uniform/wave)
      int sec = gc >> 6;
      int d = gc & 63;
      int rb = wm2 * 32 + mt * 16 + lg * 4;
      if (sec == 0) {
        float bq = q_b[n * 64 + d];
        #pragma unroll
        for (int r = 0; r < 4; ++r) {
          int row = rb + r;
          Qs[row * 64 + (((d >> 3) ^ (row & 7)) << 3) + (d & 7)] =
              (bf16)(acc[mt][nt][r] + bq);
        }
      } else if (sec == 1) {
        float bk = k_b[n * 64 + d];
        #pragma unroll
        for (int r = 0; r < 4; ++r) {
          int row = rb + r;               // token j
          float kv = acc[mt][nt][r] + bk;
          KP[row * 128 + (((d >> 3) ^ (row & 7)) << 3) + (d & 7)] =
              (bf16)(kv + (float)pqb[row * 64 + d]);
          int d2 = 64 + d;
          KP[row * 128 + (((d2 >> 3) ^ (row & 7)) << 3) + (d2 & 7)] = (bf16)kv;
        }
      }
      // sec == 2: V kept in acc until after S-phase
    }
  }
  __syncthreads();

  // ---------------- Phase 3a: S = [q | pk'] @ KP^T ----------------
  const int i0 = wv * 16;
  fvec4 s[8];
  #pragma unroll
  for (int i = 0; i < 8; ++i) s[i] = zero4();
  #pragma unroll
  for (int kc = 0; kc < 4; ++kc) {
    bf16x8 af;
    if (kc < 2) {
      int row = i0 + lr;
      int cs = (kc * 4 + lg) ^ (row & 7);
      af = *(const bf16x8*)(Qs + row * 64 + cs * 8);
    } else {
      af = *(const bf16x8*)(pkb + (i0 + lr) * 64 + (kc - 2) * 32 + lg * 8);
    }
    #pragma unroll
    for (int jt = 0; jt < 8; ++jt) {
      int row = jt * 16 + lr;
      int cs = (kc * 4 + lg) ^ (row & 7);
      bf16x8 bfr = *(const bf16x8*)(KP + row * 128 + cs * 8);
      s[jt] = MFMA16(af, bfr, s[jt]);
    }
  }

  const float scale = 0.125f;
  float inv[4];
  #pragma unroll
  for (int r = 0; r < 4; ++r) {
    float m = -1e30f;
    #pragma unroll
    for (int jt = 0; jt < 8; ++jt) m = fmaxf(m, s[jt][r]);
    #pragma unroll
    for (int off = 1; off < 16; off <<= 1) m = fmaxf(m, __shfl_xor(m, off));
    float sm = 0.f;
    #pragma unroll
    for (int jt = 0; jt < 8; ++jt) {
      float e = __expf((s[jt][r] - m) * scale);
      s[jt][r] = e;
      sm += e;
    }
    #pragma unroll
    for (int off = 1; off < 16; off <<= 1) sm += __shfl_xor(sm, off);
    inv[r] = 1.f / sm;
  }
  __syncthreads();   // Qs + KP reads done

  // P -> KP (swizzled), Vmix^T -> Vt (Qs region, now dead)
  #pragma unroll
  for (int r = 0; r < 4; ++r) {
    int i = i0 + lg * 4 + r;
    #pragma unroll
    for (int jt = 0; jt < 8; ++jt) {
      int j = jt * 16 + lr;
      KP[i * 128 + (((j >> 3) ^ (i & 7)) << 3) + (j & 7)] =
          (bf16)(s[jt][r] * inv[r]);
    }
  }
  if (wn2 == 1) {
    #pragma unroll
    for (int mt = 0; mt < 2; ++mt) {
      #pragma unroll
      for (int nt = 2; nt < 6; ++nt) {
        int d = nt * 16 - 32 + lr;        // 0..63
        float bv = v_b[n * 64 + d];
        #pragma unroll
        for (int r = 0; r < 4; ++r) {
          int j = wm2 * 32 + mt * 16 + lg * 4 + r;   // token
          float vv = gv1 * (acc[mt][nt][r] + bv) + (float)pvb[j * 64 + d];
          Vt[d * 128 + (((j >> 3) ^ (d & 7)) << 3) + (j & 7)] = (bf16)vv;
        }
      }
    }
  }
  __syncthreads();

  // ---------------- Phase 3b: O = P @ Vmix ----------------
  fvec4 o[4];
  #pragma unroll
  for (int i = 0; i < 4; ++i) o[i] = zero4();
  #pragma unroll
  for (int kc = 0; kc < 4; ++kc) {
    int prow = i0 + lr;
    int pcs = (kc * 4 + lg) ^ (prow & 7);
    bf16x8 af = *(const bf16x8*)(KP + prow * 128 + pcs * 8);
    #pragma unroll
    for (int dt = 0; dt < 4; ++dt) {
      int vr = dt * 16 + lr;
      int vcs = (kc * 4 + lg) ^ (vr & 7);
      bf16x8 bfr = *(const bf16x8*)(Vt + vr * 128 + vcs * 8);
      o[dt] = MFMA16(af, bfr, o[dt]);
    }
  }
  #pragma unroll
  for (int dt = 0; dt < 4; ++dt) {
    #pragma unroll
    for (int r = 0; r < 4; ++r) {
      int i = i0 + lg * 4 + r;
      ao[((size_t)lb * 128 + i) * 512 + n * 64 + dt * 16 + lr] = (bf16)o[dt][r];
    }
  }
}

// ---------------------------------------------------------------------------
// O-proj GEMM: A = wo (m=co), B = ao rows (n=w). Epilogue adds o_b,
// writes out[b][co][h][w]. 1D grid + XCD swizzle. (unchanged)
// ---------------------------------------------------------------------------
__global__ __launch_bounds__(256, 3) void oproj_kernel(
    const bf16* __restrict__ ao, const bf16* __restrict__ wo,
    const float* __restrict__ o_b, float* __restrict__ out, int bh0)
{
  __shared__ bf16 As[128 * 64];
  __shared__ bf16 Bs[128 * 64];
  const int nwg = gridDim.x;
  int wg = blockIdx.x;
  if ((nwg & 7) == 0) wg = (wg & 7) * (nwg >> 3) + (wg >> 3);
  const int ct4 = wg & 3;                    // co tile (0..3)
  const int lb = wg >> 2;
  const int bh = bh0 + lb, b = bh >> 7, h = bh & 127;
  const int t = threadIdx.x;
  const int wv = t >> 6, lane = t & 63;
  const int lr = lane & 15, lg = lane >> 4;
  const int wm = wv >> 1, wn = wv & 1;
  const int srow = lane >> 3, c16 = lane & 7;

  fvec4 acc[4][4];
  #pragma unroll
  for (int i = 0; i < 4; ++i)
    #pragma unroll
    for (int j = 0; j < 4; ++j) acc[i][j] = zero4();

  for (int k0 = 0; k0 < 512; k0 += 64) {
    __syncthreads();
    #pragma unroll
    for (int j = 0; j < 4; ++j) {
      int seg = wv * 4 + j;
      int row = seg * 8 + srow;
      int cs = c16 ^ (row & 7);
      glds16(wo + (size_t)(ct4 * 128 + row) * 512 + k0 + cs * 8, As + seg * 512);
      glds16(ao + ((size_t)lb * 128 + row) * 512 + k0 + cs * 8, Bs + seg * 512);
    }
    __syncthreads();
    #pragma unroll
    for (int kc = 0; kc < 2; ++kc) {
      bf16x8 af[4], bfv[4];
      #pragma unroll
      for (int mt = 0; mt < 4; ++mt) {
        int row = wm * 64 + mt * 16 + lr;
        int cs = (kc * 4 + lg) ^ (row & 7);
        af[mt] = *(const bf16x8*)(As + row * 64 + cs * 8);
      }
      #pragma unroll
      for (int nt = 0; nt < 4; ++nt) {
        int row = wn * 64 + nt * 16 + lr;
        int cs = (kc * 4 + lg) ^ (row & 7);
        bfv[nt] = *(const bf16x8*)(Bs + row * 64 + cs * 8);
      }
      #pragma unroll
      for (int mt = 0; mt < 4; ++mt)
        #pragma unroll
        for (int nt = 0; nt < 4; ++nt)
          acc[mt][nt] = MFMA16(af[mt], bfv[nt], acc[mt][nt]);
    }
  }
  #pragma unroll
  for (int mt = 0; mt < 4; ++mt) {
    #pragma unroll
    for (int r = 0; r < 4; ++r) {
      int co = ct4 * 128 + wm * 64 + mt * 16 + lg * 4 + r;
      float bv = o_b[co];
      size_t ob = ((size_t)(b * 512 + co) * 128 + h) * 128;
      #pragma unroll
      for (int nt = 0; nt < 4; ++nt) {
        int w = wn * 64 + nt * 16 + lr;
        out[ob + w] = acc[mt][nt][r] + bv;
      }
    }
  }
}

// ---------------------------------------------------------------------------
extern "C" void kernel_launch(void* const* d_in, const int* in_sizes, int n_in,
                              void* d_out, int out_size, void* d_ws, size_t ws_size,
                              hipStream_t stream) {
  const float* x    = (const float*)d_in[0];
  const float* q_w  = (const float*)d_in[1];
  const float* q_b  = (const float*)d_in[2];
  const float* k_w  = (const float*)d_in[3];
  const float* k_b  = (const float*)d_in[4];
  const float* v_w  = (const float*)d_in[5];
  const float* v_b  = (const float*)d_in[6];
  const float* o_w  = (const float*)d_in[7];
  const float* o_b  = (const float*)d_in[8];
  const float* pos_q = (const float*)d_in[9];
  const float* pos_k = (const float*)d_in[10];
  const float* pos_v = (const float*)d_in[11];
  const float* g_q  = (const float*)d_in[12];
  const float* g_k  = (const float*)d_in[13];
  const float* g_v1 = (const float*)d_in[14];
  const float* g_v2 = (const float*)d_in[15];
  float* out = (float*)d_out;

  bf16* prep = (bf16*)d_ws;
  bf16* wqkv = prep;                       // 786432
  bf16* wo   = prep + 786432;              // 262144
  bf16* posb = prep + 1048576;             // 196608

  bf16* rest = prep + PREP_ELEMS;
  size_t avail = (ws_size > (size_t)PREP_ELEMS * 2) ? ws_size - (size_t)PREP_ELEMS * 2 : 0;
  // per bh: ao (128*512) bf16 -> 128 KB (xt eliminated with xpose fusion)
  const size_t per_bh = (size_t)65536 * sizeof(bf16);
  int nbh = (int)(avail / per_bh);
  if (nbh > 512) nbh = 512;
  if (nbh < 1) nbh = 1;

  bf16* ao = rest;                                  // nbh*65536

  prep_kernel<<<608, 512, 0, stream>>>(q_w, k_w, v_w, o_w, pos_q, pos_k, pos_v,
                                       g_q, g_k, g_v2, prep);

  for (int bh0 = 0; bh0 < 512; bh0 += nbh) {
    int cur = (512 - bh0 < nbh) ? (512 - bh0) : nbh;
    qkvattn_kernel<<<cur * 8, 512, 0, stream>>>(x, wqkv, q_b, k_b, v_b, posb,
                                                g_v1, ao, bh0);
    oproj_kernel<<<cur * 4, 256, 0, stream>>>(ao, wo, o_b, out, bh0);
  }
}